// Round 1
// baseline (337.034 us; speedup 1.0000x reference)
//
#include <hip/hip_runtime.h>
#include <math.h>

// MultiLocalCosineLinear: B=65536 rows, D=768, C=100, P=4950 pairs.
// out layout (all float32): [0..B)  = preds (class id as float)
//                           [B..3B) = logits, row-major (B,2)
//
// R7: two structural cuts vs R6 (which was ~84 us kernel vs ~40 us HBM floor):
//  (a) weight-norms are per-PAIR (9900 values), not per-row (131072 computed
//      by R6). A tiny precompute kernel writes q[t] = sigma[t/2]/||W_row t||
//      (f64) into d_ws; the main kernel drops n0/n1 chains (24 of 48 f64
//      FMAs/lane), 2 of 4 f64 reductions, and the f64 sqrt/div epilogue.
//  (b) 2 rows per wave (32 lanes/row): every DPP scan/reduction instruction
//      now serves two rows, and each collective shrinks 6 steps -> 5
//      (shr1/2/4/8 + row_bcast15; DPP row ops never cross the 32-lane half).
// Same f64 dot/argmax math as R6 -> absmax unchanged.

#define D_DIM 768
#define C_DIM 100
#define EPS_N 1e-12

typedef float vf4 __attribute__((ext_vector_type(4)));

// ---- DPP plumbing (all control args compile-time) ----
#define ROW_SHR1    0x111
#define ROW_SHR2    0x112
#define ROW_SHR4    0x114
#define ROW_SHR8    0x118
#define ROW_BCAST15 0x142
#define ROW_BCAST31 0x143

template <int CTRL>
__device__ __forceinline__ float dpp0_f32(float v) {
    // invalid-source lanes read 0 (bound_ctrl) — neutral for sum
    return __builtin_bit_cast(float, __builtin_amdgcn_update_dpp(
        0, __builtin_bit_cast(int, v), CTRL, 0xF, 0xF, true));
}

template <int CTRL>
__device__ __forceinline__ double dpp0_f64(double v) {
    union { double d; unsigned long long u; } x; x.d = v;
    int lo = (int)(unsigned int)(x.u & 0xffffffffull);
    int hi = (int)(unsigned int)(x.u >> 32);
    int olo = __builtin_amdgcn_update_dpp(0, lo, CTRL, 0xF, 0xF, true);
    int ohi = __builtin_amdgcn_update_dpp(0, hi, CTRL, 0xF, 0xF, true);
    union { unsigned long long u; double d; } y;
    y.u = ((unsigned long long)(unsigned int)ohi << 32) | (unsigned int)olo;
    return y.d;
}

// ---- 32-lane (half-wave) sums: lanes 0-31 -> lane 31, lanes 32-63 -> lane 63.
// row_shr* stay inside each 16-lane DPP row; row_bcast15 flows row0->row1 and
// row2->row3 only, so the two halves never mix.
__device__ __forceinline__ float half_sum_f32(float v) {
    v += dpp0_f32<ROW_SHR1>(v);
    v += dpp0_f32<ROW_SHR2>(v);
    v += dpp0_f32<ROW_SHR4>(v);
    v += dpp0_f32<ROW_SHR8>(v);
    v += dpp0_f32<ROW_BCAST15>(v);
    return v;
}
__device__ __forceinline__ double half_sum_f64(double v) {
    v += dpp0_f64<ROW_SHR1>(v);
    v += dpp0_f64<ROW_SHR2>(v);
    v += dpp0_f64<ROW_SHR4>(v);
    v += dpp0_f64<ROW_SHR8>(v);
    v += dpp0_f64<ROW_BCAST15>(v);
    return v;
}
// ---- full-wave f64 sum (norm kernel): lane 63 holds the total
__device__ __forceinline__ double wave_sum_f64(double v) {
    v += dpp0_f64<ROW_SHR1>(v);
    v += dpp0_f64<ROW_SHR2>(v);
    v += dpp0_f64<ROW_SHR4>(v);
    v += dpp0_f64<ROW_SHR8>(v);
    v += dpp0_f64<ROW_BCAST15>(v);
    v += dpp0_f64<ROW_BCAST31>(v);
    return v;
}

__device__ __forceinline__ bool vi_gt(float v0, int i0, float v1, int i1) {
    // lexicographic (value desc, index asc) — matches jax.lax.top_k + stable sort
    return (v0 > v1) || (v0 == v1 && i0 < i1);
}

__device__ __forceinline__ void push2(float& v1, int& i1, float& v2, int& i2,
                                      float v, int i) {
    if (vi_gt(v, i, v1, i1)) { v2 = v1; i2 = i1; v1 = v; i1 = i; }
    else if (vi_gt(v, i, v2, i2)) { v2 = v; i2 = i; }
}

// one DPP scan step of the top-2 merge within a 32-lane half
template <int CTRL>
__device__ __forceinline__ void t2_step(float& v1, int& i1, float& v2, int& i2) {
    const int NEGINF = 0xFF800000;       // bits of -inf
    const int BIGIDX = 0x7fffffff;
    float ov1 = __builtin_bit_cast(float, __builtin_amdgcn_update_dpp(
        NEGINF, __builtin_bit_cast(int, v1), CTRL, 0xF, 0xF, false));
    int   oi1 = __builtin_amdgcn_update_dpp(BIGIDX, i1, CTRL, 0xF, 0xF, false);
    float ov2 = __builtin_bit_cast(float, __builtin_amdgcn_update_dpp(
        NEGINF, __builtin_bit_cast(int, v2), CTRL, 0xF, 0xF, false));
    int   oi2 = __builtin_amdgcn_update_dpp(BIGIDX, i2, CTRL, 0xF, 0xF, false);
    if (vi_gt(ov1, oi1, v1, i1)) {
        float nv2; int ni2;
        if (vi_gt(v1, i1, ov2, oi2)) { nv2 = v1;  ni2 = i1; }
        else                         { nv2 = ov2; ni2 = oi2; }
        v1 = ov1; i1 = oi1; v2 = nv2; i2 = ni2;
    } else {
        if (vi_gt(ov1, oi1, v2, i2)) { v2 = ov1; i2 = oi1; }
    }
}

// ---------------------------------------------------------------------------
// Kernel A: per-weight-row q[t] = sigma[t/2] / max(||weights[t,:]||, eps), f64.
// One wave per row t in [0, 2P); trivially small (9900 waves, 30 MB read).
// ---------------------------------------------------------------------------
__global__ __launch_bounds__(256) void norm_kernel(
    const float* __restrict__ weights,
    const float* __restrict__ sigma,
    double* __restrict__ q,
    int P2)
{
    const int lane = threadIdx.x & 63;
    const int t = (blockIdx.x << 2) + (threadIdx.x >> 6);
    if (t >= P2) return;

    const vf4* wv = (const vf4*)(weights + (size_t)t * D_DIM);
    vf4 a0 = wv[lane], a1 = wv[lane + 64], a2 = wv[lane + 128];

    double n = 0.0;
#define SQ(a)                                                                  \
    n += (double)a.x * a.x + (double)a.y * a.y                                 \
       + (double)a.z * a.z + (double)a.w * a.w;
    SQ(a0) SQ(a1) SQ(a2)
#undef SQ
    n = wave_sum_f64(n);
    if (lane == 63) {
        q[t] = (double)sigma[t >> 1] / fmax(sqrt(n), EPS_N);
    }
}

// ---------------------------------------------------------------------------
// Kernel B: main. 2 rows per wave (lanes 0-31 -> row r, lanes 32-63 -> r+1).
// ---------------------------------------------------------------------------
__global__ __launch_bounds__(256) void mlcl_kernel(
    const float* __restrict__ x,
    const float* __restrict__ first_out,
    const float* __restrict__ weights,
    const double* __restrict__ q,
    float* __restrict__ out,
    int B)
{
    const int lane = threadIdx.x & 63;
    const int half = lane >> 5;
    const int hl   = lane & 31;
    const int r = (blockIdx.x << 3) + ((threadIdx.x >> 6) << 1) + half;
    if (r >= B) return;   // B multiple of 8 in practice; guard is cold

    // ---------- candidate loads for top-2 (issue first: scan depends on them)
    const float* fo = first_out + (size_t)r * C_DIM;
    float c0 = fo[hl];
    float c1 = fo[hl + 32];
    float c2 = fo[hl + 64];
    float c3; int ic3;
    if (hl + 96 < C_DIM) { c3 = fo[hl + 96]; ic3 = hl + 96; }
    else                 { c3 = -INFINITY;   ic3 = 0x7fffffff; }

    // ---------- x loads issued early (independent of the scan) ----------
    const vf4* xv = (const vf4*)(x + (size_t)r * D_DIM);
    vf4 xa0 = xv[hl],       xa1 = xv[hl + 32],  xa2 = xv[hl + 64],
        xa3 = xv[hl + 96],  xa4 = xv[hl + 128], xa5 = xv[hl + 160];

    // ---------- top-2 of first_out[r, 0:100] via 5-step DPP scan ----------
    float v1 = c0, v2 = -INFINITY;
    int   i1 = hl, i2 = 0x7fffffff;
    push2(v1, i1, v2, i2, c1, hl + 32);
    push2(v1, i1, v2, i2, c2, hl + 64);
    push2(v1, i1, v2, i2, c3, ic3);

    t2_step<ROW_SHR1>(v1, i1, v2, i2);
    t2_step<ROW_SHR2>(v1, i1, v2, i2);
    t2_step<ROW_SHR4>(v1, i1, v2, i2);
    t2_step<ROW_SHR8>(v1, i1, v2, i2);
    t2_step<ROW_BCAST15>(v1, i1, v2, i2);
    // lane 31 holds row r's top-2 (half 0), lane 63 holds row r+1's (half 1)
    const int i1lo = __builtin_amdgcn_readlane(i1, 31);
    const int i2lo = __builtin_amdgcn_readlane(i2, 31);
    const int i1hi = __builtin_amdgcn_readlane(i1, 63);
    const int i2hi = __builtin_amdgcn_readlane(i2, 63);
    const int gi1 = half ? i1hi : i1lo;
    const int gi2 = half ? i2hi : i2lo;
    const int a = min(gi1, gi2);
    const int b = max(gi1, gi2);
    const int p = b * (b - 1) / 2 + a;

    // per-pair precomputed sigma/||W|| (f64), issued before the dot loop
    const double* qp = q + 2 * (size_t)p;
    const double q0 = qp[0];
    const double q1 = qp[1];

    // ---------- weight loads (per-half base; 512B contiguous per half) ----
    const vf4* wv = (const vf4*)(weights + (size_t)p * (2 * D_DIM));
    vf4 w00 = wv[hl],       w01 = wv[hl + 32],  w02 = wv[hl + 64],
        w03 = wv[hl + 96],  w04 = wv[hl + 128], w05 = wv[hl + 160];
    vf4 w10 = wv[192 + hl],       w11 = wv[192 + hl + 32],  w12 = wv[192 + hl + 64],
        w13 = wv[192 + hl + 96],  w14 = wv[192 + hl + 128], w15 = wv[192 + hl + 160];

    float  xx = 0.f;                 // common positive scale — f32 ok
    double d0 = 0.0, d1 = 0.0;       // feed argmax — f64 (same as R6)
#define ACC(xa, w0, w1)                                                       \
    xx += xa.x * xa.x + xa.y * xa.y + xa.z * xa.z + xa.w * xa.w;              \
    d0 += (double)xa.x * w0.x + (double)xa.y * w0.y                           \
        + (double)xa.z * w0.z + (double)xa.w * w0.w;                          \
    d1 += (double)xa.x * w1.x + (double)xa.y * w1.y                           \
        + (double)xa.z * w1.z + (double)xa.w * w1.w;
    ACC(xa0, w00, w10)
    ACC(xa1, w01, w11)
    ACC(xa2, w02, w12)
    ACC(xa3, w03, w13)
    ACC(xa4, w04, w14)
    ACC(xa5, w05, w15)
#undef ACC

    xx = half_sum_f32(xx);
    d0 = half_sum_f64(d0);
    d1 = half_sum_f64(d1);

    // ---------- epilogue on lanes 31 / 63 (each half's sums) ----------
    if (hl == 31) {
        const double inx = 1.0 / fmax(sqrt((double)xx), EPS_N);
        const double l0  = q0 * d0 * inx;
        const double l1  = q1 * d1 * inx;
        const int sel = (l1 > l0) ? 1 : 0;   // jnp.argmax: first index wins ties
        out[r] = (float)(sel ? b : a);
        float2 lg = make_float2((float)l0, (float)l1);
        *(float2*)(out + B + 2 * (size_t)r) = lg;    // 8B-aligned: B even
    }
}

extern "C" void kernel_launch(void* const* d_in, const int* in_sizes, int n_in,
                              void* d_out, int out_size, void* d_ws, size_t ws_size,
                              hipStream_t stream) {
    const float* x         = (const float*)d_in[0];
    const float* first_out = (const float*)d_in[1];
    const float* weights   = (const float*)d_in[2];
    const float* sigma     = (const float*)d_in[3];
    float* out = (float*)d_out;
    double* q  = (double*)d_ws;            // 2P doubles = 79.2 KB

    const int B  = in_sizes[0] / D_DIM;    // 65536
    const int P2 = in_sizes[2] / D_DIM;    // 2*P = 9900

    hipLaunchKernelGGL(norm_kernel, dim3((P2 + 3) / 4), dim3(256), 0, stream,
                       weights, sigma, q, P2);
    hipLaunchKernelGGL(mlcl_kernel, dim3((B + 7) / 8), dim3(256), 0, stream,
                       x, first_out, weights, sigma == nullptr ? nullptr : q, out, B);
}

// Round 2
// 321.439 us; speedup vs baseline: 1.0485x; 1.0485x over previous
//
#include <hip/hip_runtime.h>
#include <math.h>

// MultiLocalCosineLinear: B=65536 rows, D=768, C=100, P=4950 pairs.
// out layout (all float32): [0..B)  = preds (class id as float)
//                           [B..3B) = logits, row-major (B,2)
//
// R8: R6 structure (1 row/wave, wave-uniform pair index p -> scalar weight
// base + s_load for q) + R7's per-pair norm precompute.
//   norm_kernel: q[t] = sigma[t/2] / max(||weights[t,:]||, eps)  (f64, d_ws)
//   mlcl_kernel: drops n0/n1 chains (24 of 48 f64 FMAs/lane), 2 of 5
//                reductions, and the f64 sqrt/divs in the epilogue.
// vs R7 (337 us, regression): 2-rows-per-wave made p divergent -> vector
// address math on all 12 weight loads + ~2x live VGPRs. Reverted.
// x loads hoisted ABOVE the top-2 scan: no dependency on p, ~500 cyc of
// global-load latency hides under the scan.

#define D_DIM 768
#define C_DIM 100
#define EPS_N 1e-12

typedef float vf4 __attribute__((ext_vector_type(4)));

// ---- DPP plumbing (all control args compile-time) ----
#define ROW_SHR1    0x111
#define ROW_SHR2    0x112
#define ROW_SHR4    0x114
#define ROW_SHR8    0x118
#define ROW_BCAST15 0x142
#define ROW_BCAST31 0x143

template <int CTRL>
__device__ __forceinline__ float dpp0_f32(float v) {
    // invalid-source lanes read 0 (bound_ctrl) — neutral for sum
    return __builtin_bit_cast(float, __builtin_amdgcn_update_dpp(
        0, __builtin_bit_cast(int, v), CTRL, 0xF, 0xF, true));
}

template <int CTRL>
__device__ __forceinline__ double dpp0_f64(double v) {
    union { double d; unsigned long long u; } x; x.d = v;
    int lo = (int)(unsigned int)(x.u & 0xffffffffull);
    int hi = (int)(unsigned int)(x.u >> 32);
    int olo = __builtin_amdgcn_update_dpp(0, lo, CTRL, 0xF, 0xF, true);
    int ohi = __builtin_amdgcn_update_dpp(0, hi, CTRL, 0xF, 0xF, true);
    union { unsigned long long u; double d; } y;
    y.u = ((unsigned long long)(unsigned int)ohi << 32) | (unsigned int)olo;
    return y.d;
}

__device__ __forceinline__ float wave_sum_f32(float v) {
    v += dpp0_f32<ROW_SHR1>(v);
    v += dpp0_f32<ROW_SHR2>(v);
    v += dpp0_f32<ROW_SHR4>(v);
    v += dpp0_f32<ROW_SHR8>(v);
    v += dpp0_f32<ROW_BCAST15>(v);
    v += dpp0_f32<ROW_BCAST31>(v);
    return v;                       // lane 63 holds the full wave sum
}

__device__ __forceinline__ double wave_sum_f64(double v) {
    v += dpp0_f64<ROW_SHR1>(v);
    v += dpp0_f64<ROW_SHR2>(v);
    v += dpp0_f64<ROW_SHR4>(v);
    v += dpp0_f64<ROW_SHR8>(v);
    v += dpp0_f64<ROW_BCAST15>(v);
    v += dpp0_f64<ROW_BCAST31>(v);
    return v;                       // lane 63 holds the full wave sum
}

__device__ __forceinline__ bool vi_gt(float v0, int i0, float v1, int i1) {
    // lexicographic (value desc, index asc) — matches jax.lax.top_k + stable sort
    return (v0 > v1) || (v0 == v1 && i0 < i1);
}

// one DPP scan step of the top-2 merge: pull partner's (v1,i1,v2,i2) via DPP
// (invalid lanes see (-inf, INT_MAX) — neutral), merge into local top-2.
template <int CTRL>
__device__ __forceinline__ void t2_step(float& v1, int& i1, float& v2, int& i2) {
    const int NEGINF = 0xFF800000;       // bits of -inf
    const int BIGIDX = 0x7fffffff;
    float ov1 = __builtin_bit_cast(float, __builtin_amdgcn_update_dpp(
        NEGINF, __builtin_bit_cast(int, v1), CTRL, 0xF, 0xF, false));
    int   oi1 = __builtin_amdgcn_update_dpp(BIGIDX, i1, CTRL, 0xF, 0xF, false);
    float ov2 = __builtin_bit_cast(float, __builtin_amdgcn_update_dpp(
        NEGINF, __builtin_bit_cast(int, v2), CTRL, 0xF, 0xF, false));
    int   oi2 = __builtin_amdgcn_update_dpp(BIGIDX, i2, CTRL, 0xF, 0xF, false);
    if (vi_gt(ov1, oi1, v1, i1)) {
        float nv2; int ni2;
        if (vi_gt(v1, i1, ov2, oi2)) { nv2 = v1;  ni2 = i1; }
        else                         { nv2 = ov2; ni2 = oi2; }
        v1 = ov1; i1 = oi1; v2 = nv2; i2 = ni2;
    } else {
        if (vi_gt(ov1, oi1, v2, i2)) { v2 = ov1; i2 = oi1; }
    }
}

// ---------------------------------------------------------------------------
// Kernel A: per-weight-row q[t] = sigma[t/2] / max(||weights[t,:]||, eps), f64.
// One wave per row t in [0, 2P); 9900 waves, 30 MB read. Also warms L3 for
// the main kernel's weight reads.
// ---------------------------------------------------------------------------
__global__ __launch_bounds__(256) void norm_kernel(
    const float* __restrict__ weights,
    const float* __restrict__ sigma,
    double* __restrict__ q,
    int P2)
{
    const int lane = threadIdx.x & 63;
    const int t = (blockIdx.x << 2) + (threadIdx.x >> 6);
    if (t >= P2) return;

    const vf4* wv = (const vf4*)(weights + (size_t)t * D_DIM);
    vf4 a0 = wv[lane], a1 = wv[lane + 64], a2 = wv[lane + 128];

    double n = 0.0;
#define SQ(a)                                                                  \
    n += (double)a.x * a.x + (double)a.y * a.y                                 \
       + (double)a.z * a.z + (double)a.w * a.w;
    SQ(a0) SQ(a1) SQ(a2)
#undef SQ
    n = wave_sum_f64(n);
    if (lane == 63) {
        q[t] = (double)sigma[t >> 1] / fmax(sqrt(n), EPS_N);
    }
}

// ---------------------------------------------------------------------------
// Kernel B: main. 1 row per wave, wave-uniform p.
// ---------------------------------------------------------------------------
__global__ __launch_bounds__(256) void mlcl_kernel(
    const float* __restrict__ x,
    const float* __restrict__ first_out,
    const float* __restrict__ weights,
    const double* __restrict__ q,
    float* __restrict__ out,
    int B)
{
    const int lane = threadIdx.x & 63;
    const int r = (blockIdx.x << 2) + (threadIdx.x >> 6);
    if (r >= B) return;

    // ---------- issue fo + x loads first (x has no dependency on the scan;
    // its ~500cy latency hides under the top-2 scan) ----------
    const float* fo = first_out + (size_t)r * C_DIM;
    float e0 = fo[lane];
    int   j1 = lane + 64;
    float e1 = (j1 < C_DIM) ? fo[j1] : -INFINITY;

    const vf4* xv = (const vf4*)(x + (size_t)r * D_DIM);
    vf4 xa0 = xv[lane], xa1 = xv[lane + 64], xa2 = xv[lane + 128];

    // ---------- top-2 of first_out[r, 0:100] via DPP scan ----------
    float v1, v2; int i1, i2;
    if (vi_gt(e1, j1, e0, lane)) { v1 = e1; i1 = j1;   v2 = e0; i2 = lane; }
    else                         { v1 = e0; i1 = lane; v2 = e1; i2 = j1; }

    t2_step<ROW_SHR1>(v1, i1, v2, i2);
    t2_step<ROW_SHR2>(v1, i1, v2, i2);
    t2_step<ROW_SHR4>(v1, i1, v2, i2);
    t2_step<ROW_SHR8>(v1, i1, v2, i2);
    t2_step<ROW_BCAST15>(v1, i1, v2, i2);
    t2_step<ROW_BCAST31>(v1, i1, v2, i2);
    // lane 63 holds the global top-2; readlane -> SGPR, wave-uniform
    const int gi1 = __builtin_amdgcn_readlane(i1, 63);
    const int gi2 = __builtin_amdgcn_readlane(i2, 63);
    const int a = min(gi1, gi2);
    const int b = max(gi1, gi2);
    const int p = b * (b - 1) / 2 + a;

    // per-pair precomputed sigma/||W|| (f64); uniform p -> s_load, hides
    // under the dot loop
    const double q0 = q[2 * (size_t)p];
    const double q1 = q[2 * (size_t)p + 1];

    // ---------- weight loads (uniform base -> saddr form) ----------
    const vf4* wv = (const vf4*)(weights + (size_t)p * (2 * D_DIM));
    vf4 w00 = wv[lane],       w01 = wv[lane + 64],       w02 = wv[lane + 128];
    vf4 w10 = wv[192 + lane], w11 = wv[192 + lane + 64], w12 = wv[192 + lane + 128];

    float  xx = 0.f;                 // common positive scale — f32 ok
    double d0 = 0.0, d1 = 0.0;       // feed argmax — f64
#define ACC(xa, w0, w1)                                                       \
    xx += xa.x * xa.x + xa.y * xa.y + xa.z * xa.z + xa.w * xa.w;              \
    d0 += (double)xa.x * w0.x + (double)xa.y * w0.y                           \
        + (double)xa.z * w0.z + (double)xa.w * w0.w;                          \
    d1 += (double)xa.x * w1.x + (double)xa.y * w1.y                           \
        + (double)xa.z * w1.z + (double)xa.w * w1.w;
    ACC(xa0, w00, w10)
    ACC(xa1, w01, w11)
    ACC(xa2, w02, w12)
#undef ACC

    xx = wave_sum_f32(xx);
    d0 = wave_sum_f64(d0);
    d1 = wave_sum_f64(d1);

    // ---------- epilogue on lane 63 (holds the sums) ----------
    if (lane == 63) {
        const double inx = 1.0 / fmax(sqrt((double)xx), EPS_N);
        const double l0  = q0 * d0 * inx;
        const double l1  = q1 * d1 * inx;
        const int sel = (l1 > l0) ? 1 : 0;   // jnp.argmax: first index wins ties
        out[r] = (float)(sel ? b : a);
        float2 lg = make_float2((float)l0, (float)l1);
        *(float2*)(out + B + 2 * (size_t)r) = lg;    // 8B-aligned: B even
    }
}

extern "C" void kernel_launch(void* const* d_in, const int* in_sizes, int n_in,
                              void* d_out, int out_size, void* d_ws, size_t ws_size,
                              hipStream_t stream) {
    const float* x         = (const float*)d_in[0];
    const float* first_out = (const float*)d_in[1];
    const float* weights   = (const float*)d_in[2];
    const float* sigma     = (const float*)d_in[3];
    float* out = (float*)d_out;
    double* q  = (double*)d_ws;            // 2P doubles = 79.2 KB

    const int B  = in_sizes[0] / D_DIM;    // 65536
    const int P2 = in_sizes[2] / D_DIM;    // 2*P = 9900

    hipLaunchKernelGGL(norm_kernel, dim3((P2 + 3) / 4), dim3(256), 0, stream,
                       weights, sigma, q, P2);
    hipLaunchKernelGGL(mlcl_kernel, dim3((B + 3) / 4), dim3(256), 0, stream,
                       x, first_out, weights, q, out, B);
}